// Round 10
// baseline (310.528 us; speedup 1.0000x reference)
//
#include <hip/hip_runtime.h>

#define BB 64
#define CC 96
#define HH 56
#define WW 56
#define HWSZ (HH*WW)          // 3136
#define CHW (CC*HWSZ)         // 301056
#define NTOT ((size_t)BB*CHW) // 19267584
#define S_SPLIT 32
#define CHUNK (CHW/S_SPLIT)   // 9408
#define HD 384
#define NP 104                // LDS row pitch (ushorts): 208B rows, 16B-aligned

typedef float f32x4  __attribute__((ext_vector_type(4)));
typedef short bf16x8 __attribute__((ext_vector_type(8)));
typedef unsigned short u16x4 __attribute__((ext_vector_type(4)));

__device__ __forceinline__ unsigned short f2bf(float f) {
    unsigned int u = __float_as_uint(f);
    u = (u + 0x7FFFu + ((u >> 16) & 1u)) >> 16;   // RNE
    return (unsigned short)u;
}
__device__ __forceinline__ float bf2f(unsigned short u) {
    return __uint_as_float(((unsigned int)u) << 16);
}
// tanh-approx GELU: |err| vs exact erf-gelu ~1e-3.
__device__ __forceinline__ float gelu_t(float x) {
    float s = x*x;
    float q = __builtin_fmaf(s, 0.102943f, 2.3021953f) * x;   // 2y*log2e
    float t = exp2f(q);
    float r = __builtin_amdgcn_rcpf(1.0f + t);
    return __builtin_fmaf(-x, r, x);                          // x - x/(1+e^{2y})
}
__device__ __forceinline__ bf16x8 ldfrag(const unsigned short* p) {
    return *reinterpret_cast<const bf16x8*>(p);
}
// volatile async global load: cannot be sunk/deleted by the compiler.
// Consumer MUST wait via wait_vm<N>() before reading d (compiler does not track this load).
__device__ __forceinline__ void ldg_async(bf16x8& d, const unsigned short* p) {
    asm volatile("global_load_dwordx4 %0, %1, off" : "=&v"(d) : "v"(p));
}
// explicit vmcnt wait + scheduler fence (rule #18: sched_barrier after waitcnt,
// else register-only MFMA can be hoisted past the wait).
template<int N>
__device__ __forceinline__ void wait_vm() {
    asm volatile("s_waitcnt vmcnt(%0)" :: "i"(N) : "memory");
    __builtin_amdgcn_sched_barrier(0);
}
// inline GN-stats finalize: every wave reduces the producer's partial sums itself
template<int NPART>
__device__ __forceinline__ float2 stats_from_parts(const float2* __restrict__ part, int b) {
    int lane = threadIdx.x & 63;
    float s = 0.f, q = 0.f;
    for (int i = lane; i < NPART; i += 64) {
        float2 v = part[b*NPART + i];
        s += v.x; q += v.y;
    }
    #pragma unroll
    for (int off = 32; off > 0; off >>= 1) {
        s += __shfl_down(s, off);
        q += __shfl_down(q, off);
    }
    s = __shfl(s, 0); q = __shfl(q, 0);
    float mean = s / (float)CHW;
    float var  = q / (float)CHW - mean*mean;
    return make_float2(mean, rsqrtf(var + 1e-5f));
}

// ================= weight pre-convert + MFMA-fragment repack (once) =================
__global__ __launch_bounds__(256) void wconv(const float* __restrict__ c1w, const float* __restrict__ c21w,
        const float* __restrict__ c22w, const float* __restrict__ c3w,
        const float* __restrict__ f1w, const float* __restrict__ f2w,
        unsigned short* __restrict__ wbf) {
    int i = blockIdx.x*256 + threadIdx.x;           // 110592 total
    int blk = i / 9216;
    int idx = i - blk*9216;
    int tm   = idx / 1536;
    int rem  = idx - tm*1536;
    int ks   = rem / 512;
    int rem2 = rem - ks*512;
    int lane = rem2 >> 3;
    int j    = rem2 & 7;
    int row = tm*16 + (lane & 15);
    int col = ks*32 + (lane >> 4)*8 + j;
    float v;
    if      (blk == 0) v = c1w [row*CC + col];
    else if (blk == 1) v = c21w[row*CC + col];
    else if (blk == 2) v = c22w[row*CC + col];
    else if (blk == 3) v = c3w [row*CC + col];
    else if (blk <  8) v = f1w[((blk-4)*CC + row)*CC + col];
    else               v = f2w[row*HD + (blk-8)*CC + col];
    wbf[i] = f2bf(v);
}

// ================= GN stats on x, float4 =================
__global__ __launch_bounds__(256) void gn_partial(const float* __restrict__ in, float2* __restrict__ part) {
    int b = blockIdx.y, s = blockIdx.x;
    const float4* p = (const float4*)(in + (size_t)b*CHW + (size_t)s*CHUNK);
    float sum = 0.f, sq = 0.f;
    for (int i = threadIdx.x; i < CHUNK/4; i += 256) {
        float4 v = p[i];
        sum += v.x+v.y+v.z+v.w;
        sq  += v.x*v.x+v.y*v.y+v.z*v.z+v.w*v.w;
    }
    #pragma unroll
    for (int off = 32; off > 0; off >>= 1) {
        sum += __shfl_down(sum, off);
        sq  += __shfl_down(sq,  off);
    }
    __shared__ float2 red[4];
    int wid = threadIdx.x >> 6, lane = threadIdx.x & 63;
    if (lane == 0) red[wid] = make_float2(sum, sq);
    __syncthreads();
    if (threadIdx.x == 0) {
        for (int i = 1; i < 4; i++) { sum += red[i].x; sq += red[i].y; }
        part[b*S_SPLIT + s] = make_float2(sum, sq);
    }
}

// ================= batch-paired 1x1 conv, M-split waves, weight frags pre-hoisted =================
template<bool IN_BF, bool OUT_RES, int NPART>
__global__ __launch_bounds__(256) void convk(const void* __restrict__ in_,
        const unsigned short* __restrict__ wbf, const float* __restrict__ bias,
        const float2* __restrict__ part_in, const float* __restrict__ gam, const float* __restrict__ bet,
        const float* __restrict__ res, void* __restrict__ out_, float2* __restrict__ part_out) {
    __shared__ unsigned short xs[128][NP];
    __shared__ float gml[CC], btl[CC];
    __shared__ float2 red[4];
    int tid = threadIdx.x;
    int b0 = blockIdx.y, b1 = b0 + 32;
    int hw0 = blockIdx.x * 64;
    int lane = tid & 63, wv = tid >> 6;
    int mh = wv >> 1, cg = wv & 1;
    // hoist weight frags: latency covered by stats reduce + staging + barrier
    bf16x8 wfr[9];
    {
        const unsigned short* wl = wbf + mh*4608 + lane*8;
        #pragma unroll
        for (int i = 0; i < 9; i++) wfr[i] = ldfrag(wl + i*512);
    }
    float2 st0 = stats_from_parts<NPART>(part_in, b0);
    float2 st1 = stats_from_parts<NPART>(part_in, b1);
    if (tid < CC) { gml[tid] = gam[tid]; btl[tid] = bet[tid]; }
    __syncthreads();
    int col = tid & 63;
    for (int c4 = (tid >> 6)*4; c4 < CC; c4 += 16) {
        unsigned int pk0[2], pk1[2];
        #pragma unroll
        for (int j = 0; j < 4; j++) {
            int c = c4 + j;
            size_t off0 = (size_t)b0*CHW + (size_t)c*HWSZ + hw0 + col;
            size_t off1 = (size_t)b1*CHW + (size_t)c*HWSZ + hw0 + col;
            float r0 = IN_BF ? bf2f(((const unsigned short*)in_)[off0]) : ((const float*)in_)[off0];
            float r1 = IN_BF ? bf2f(((const unsigned short*)in_)[off1]) : ((const float*)in_)[off1];
            float a0 = st0.y * gml[c], b0c = __builtin_fmaf(-st0.x, a0, btl[c]);
            float a1 = st1.y * gml[c], b1c = __builtin_fmaf(-st1.x, a1, btl[c]);
            unsigned short h0 = f2bf(__builtin_fmaf(r0, a0, b0c));
            unsigned short h1 = f2bf(__builtin_fmaf(r1, a1, b1c));
            if (j < 2) { if (j == 0) { pk0[0] = h0; pk1[0] = h1; } else { pk0[0] |= (unsigned int)h0 << 16; pk1[0] |= (unsigned int)h1 << 16; } }
            else       { if (j == 2) { pk0[1] = h0; pk1[1] = h1; } else { pk0[1] |= (unsigned int)h0 << 16; pk1[1] |= (unsigned int)h1 << 16; } }
        }
        *reinterpret_cast<uint2*>(&xs[col][c4])      = make_uint2(pk0[0], pk0[1]);
        *reinterpret_cast<uint2*>(&xs[64+col][c4])   = make_uint2(pk1[0], pk1[1]);
    }
    __syncthreads();
    int ln = lane & 15, k0 = (lane >> 4)*8, r0i = (lane >> 4)*4;
    f32x4 acc[3][4];
    #pragma unroll
    for (int t = 0; t < 3; t++)
        #pragma unroll
        for (int x = 0; x < 4; x++) acc[t][x] = (f32x4){0,0,0,0};
    __builtin_amdgcn_s_setprio(1);
    #pragma unroll
    for (int ks = 0; ks < 3; ks++) {
        bf16x8 bfr[4];
        #pragma unroll
        for (int xr = 0; xr < 4; xr++) bfr[xr] = ldfrag(&xs[cg*64 + xr*16 + ln][ks*32+k0]);
        #pragma unroll
        for (int tm = 0; tm < 3; tm++) {
            #pragma unroll
            for (int xr = 0; xr < 4; xr++)
                acc[tm][xr] = __builtin_amdgcn_mfma_f32_16x16x32_bf16(wfr[tm*3+ks], bfr[xr], acc[tm][xr], 0, 0, 0);
        }
    }
    __builtin_amdgcn_s_setprio(0);
    size_t obase = (size_t)(cg ? b1 : b0)*CHW + hw0;
    float s = 0.f, q = 0.f;
    #pragma unroll
    for (int tm = 0; tm < 3; tm++) {
        #pragma unroll
        for (int xr = 0; xr < 4; xr++) {
            #pragma unroll
            for (int r = 0; r < 4; r++) {
                int o = mh*48 + tm*16 + r0i + r;
                size_t idx = obase + (size_t)o*HWSZ + xr*16 + ln;
                float v = acc[tm][xr][r] + bias[o];
                if (OUT_RES) { v += res[idx]; ((float*)out_)[idx] = v; }
                else         { ((unsigned short*)out_)[idx] = f2bf(v); }
                s += v; q += v*v;
            }
        }
    }
    #pragma unroll
    for (int off = 32; off > 0; off >>= 1) { s += __shfl_down(s, off); q += __shfl_down(q, off); }
    if (lane == 0) red[wv] = make_float2(s, q);
    __syncthreads();
    if (tid == 0) {
        part_out[b0*49 + blockIdx.x] = make_float2(red[0].x + red[2].x, red[0].y + red[2].y);
        part_out[b1*49 + blockIdx.x] = make_float2(red[1].x + red[3].x, red[1].y + red[3].y);
    }
}

// ================= depthwise 3x3: fused gelu(gn(t1)), inline stats, stats epilogue =================
__global__ __launch_bounds__(256) void dw_fused(const unsigned short* __restrict__ t1,
        const float* __restrict__ dww, const float* __restrict__ dwb,
        const float2* __restrict__ part_in, const float* __restrict__ gam, const float* __restrict__ bet,
        unsigned short* __restrict__ t2, float2* __restrict__ part_out) {
    __shared__ float tile[HH*57];
    __shared__ float2 red[4];
    int bc = blockIdx.x;
    int b = bc / CC, c = bc - b*CC;
    int tid = threadIdx.x;
    float2 st = stats_from_parts<49>(part_in, b);
    float ga = gam[c]*st.y;
    float bb = __builtin_fmaf(-st.x, ga, bet[c]);
    const unsigned short* ip = t1 + (size_t)bc*HWSZ;
    for (int i = tid; i < HWSZ; i += 256) {
        float v = __builtin_fmaf(bf2f(ip[i]), ga, bb);
        tile[(i/WW)*57 + (i%WW)] = gelu_t(v);
    }
    __syncthreads();
    float w00=dww[c*9+0],w01=dww[c*9+1],w02=dww[c*9+2],
          w10=dww[c*9+3],w11=dww[c*9+4],w12=dww[c*9+5],
          w20=dww[c*9+6],w21=dww[c*9+7],w22=dww[c*9+8];
    float bs = dwb[c];
    unsigned short* op = t2 + (size_t)bc*HWSZ;
    float s = 0.f, q = 0.f;
    for (int i = tid; i < HWSZ; i += 256) {
        int h = i/WW, w_ = i - h*WW;
        float acc = bs;
        int up = h > 0, dn = h < HH-1, lf = w_ > 0, rt = w_ < WW-1;
        const float* rm = &tile[(h-1)*57 + w_];
        const float* r0p = &tile[h*57 + w_];
        const float* rp = &tile[(h+1)*57 + w_];
        if (up) { if (lf) acc += rm[-1]*w00; acc += rm[0]*w01; if (rt) acc += rm[1]*w02; }
        if (lf) acc += r0p[-1]*w10;
        acc += r0p[0]*w11;
        if (rt) acc += r0p[1]*w12;
        if (dn) { if (lf) acc += rp[-1]*w20; acc += rp[0]*w21; if (rt) acc += rp[1]*w22; }
        op[i] = f2bf(acc);
        s += acc; q += acc*acc;
    }
    #pragma unroll
    for (int off = 32; off > 0; off >>= 1) { s += __shfl_down(s, off); q += __shfl_down(q, off); }
    int wid = tid >> 6, lane = tid & 63;
    if (lane == 0) red[wid] = make_float2(s, q);
    __syncthreads();
    if (tid == 0) {
        for (int i = 1; i < 4; i++) { s += red[i].x; q += red[i].y; }
        part_out[bc] = make_float2(s, q);   // indexed [b*96+c]
    }
}

// ================= merged LIF: one gelu(gn) pass, bf16 LDS plane =================
__global__ __launch_bounds__(64) void lif_hw(const unsigned short* __restrict__ t2,
        unsigned short* __restrict__ xlr, unsigned short* __restrict__ xtd,
        const float2* __restrict__ part_in, const float* __restrict__ gam, const float* __restrict__ bet,
        const float* __restrict__ tau1p, const float* __restrict__ vth1p,
        const float* __restrict__ tau2p, const float* __restrict__ vth2p) {
    __shared__ unsigned short tile[HH*58];
    int bc = blockIdx.x;
    int b = bc / CC, c = bc - b*CC;
    int tid = threadIdx.x;
    float2 st = stats_from_parts<96>(part_in, b);
    float ga = gam[c]*st.y;
    float bb = __builtin_fmaf(-st.x, ga, bet[c]);
    const unsigned short* ip = t2 + (size_t)bc*HWSZ;
    for (int i = tid; i < HWSZ/4; i += 64) {
        u16x4 v = *reinterpret_cast<const u16x4*>(ip + i*4);
        int h = i / 14;
        int w0 = (i - h*14)*4;
        unsigned short* tp = &tile[h*58 + w0];
        #pragma unroll
        for (int j = 0; j < 4; j++)
            tp[j] = f2bf(gelu_t(__builtin_fmaf(bf2f((unsigned short)v[j]), ga, bb)));
    }
    __syncthreads();
    const float tau1 = *tau1p, vth1 = *vth1p;
    if (tid < WW) {
        float u = 0.f, o = 0.f;
        unsigned short* op = xlr + (size_t)bc*HWSZ + tid;
        for (int h = 0; h < HH; h++) {
            float xv = bf2f(tile[h*58 + tid]);
            u = xv + tau1*u*(1.f - o);
            o = (u - vth1 > 0.f) ? 1.f : 0.f;
            op[h*WW] = (o != 0.f) ? (unsigned short)0x3F80 : (unsigned short)0;
        }
    }
    __syncthreads();
    const float tau2 = *tau2p, vth2 = *vth2p;
    if (tid < HH) {
        float u = 0.f, o = 0.f;
        int off = tid*58;
        for (int w_ = 0; w_ < WW; w_++) {
            float xv = bf2f(tile[off + w_]);
            u = xv + tau2*u*(1.f - o);
            o = (u - vth2 > 0.f) ? 1.f : 0.f;
            tile[off + w_] = (o != 0.f) ? (unsigned short)0x3F80 : (unsigned short)0;
        }
    }
    __syncthreads();
    unsigned int* op32 = (unsigned int*)(xtd + (size_t)bc*HWSZ);
    for (int i = tid; i < HWSZ/2; i += 64) {
        int h = i / 28;
        int w0 = (i - h*28)*2;
        op32[i] = (unsigned int)tile[h*58 + w0] | ((unsigned int)tile[h*58 + w0 + 1] << 16);
    }
}

// ================= dual conv, M-split waves, stats epilogue =================
__global__ __launch_bounds__(256) void dual_mfma(const unsigned short* __restrict__ xa_g, const unsigned short* __restrict__ xb_g,
        const unsigned short* __restrict__ w1bf, const float* __restrict__ b1,
        const unsigned short* __restrict__ w2bf, const float* __restrict__ b2,
        unsigned short* __restrict__ out, float2* __restrict__ part_out) {
    __shared__ unsigned short xa[64][NP];
    __shared__ unsigned short xb[64][NP];
    __shared__ float2 red[4];
    int tid = threadIdx.x;
    int b = blockIdx.y;
    int hw0 = blockIdx.x * 64;
    int col = tid & 63;
    const unsigned short* ap = xa_g + (size_t)b*CHW + hw0 + col;
    const unsigned short* bp = xb_g + (size_t)b*CHW + hw0 + col;
    for (int c4 = (tid >> 6)*4; c4 < CC; c4 += 16) {
        unsigned short a0 = ap[(size_t)(c4+0)*HWSZ], a1v = ap[(size_t)(c4+1)*HWSZ];
        unsigned short a2 = ap[(size_t)(c4+2)*HWSZ], a3 = ap[(size_t)(c4+3)*HWSZ];
        unsigned short b0v = bp[(size_t)(c4+0)*HWSZ], b1v = bp[(size_t)(c4+1)*HWSZ];
        unsigned short b2v = bp[(size_t)(c4+2)*HWSZ], b3v = bp[(size_t)(c4+3)*HWSZ];
        *reinterpret_cast<uint2*>(&xa[col][c4]) =
            make_uint2((unsigned int)a0 | ((unsigned int)a1v << 16), (unsigned int)a2 | ((unsigned int)a3 << 16));
        *reinterpret_cast<uint2*>(&xb[col][c4]) =
            make_uint2((unsigned int)b0v | ((unsigned int)b1v << 16), (unsigned int)b2v | ((unsigned int)b3v << 16));
    }
    __syncthreads();
    int lane = tid & 63, wv = tid >> 6;
    int mh = wv >> 1, cg = wv & 1;
    int ln = lane & 15, k0 = (lane >> 4)*8, r0i = (lane >> 4)*4;
    const unsigned short* wl1 = w1bf + mh*4608 + lane*8;
    const unsigned short* wl2 = w2bf + mh*4608 + lane*8;
    f32x4 acc1[3][2], acc2[3][2];
    #pragma unroll
    for (int t = 0; t < 3; t++) {
        acc1[t][0] = (f32x4){0,0,0,0}; acc1[t][1] = (f32x4){0,0,0,0};
        acc2[t][0] = (f32x4){0,0,0,0}; acc2[t][1] = (f32x4){0,0,0,0};
    }
    __builtin_amdgcn_s_setprio(1);
    #pragma unroll
    for (int ks = 0; ks < 3; ks++) {
        bf16x8 bfa0 = ldfrag(&xa[cg*32 + ln][ks*32+k0]);
        bf16x8 bfa1 = ldfrag(&xa[cg*32 + 16 + ln][ks*32+k0]);
        bf16x8 bfb0 = ldfrag(&xb[cg*32 + ln][ks*32+k0]);
        bf16x8 bfb1 = ldfrag(&xb[cg*32 + 16 + ln][ks*32+k0]);
        #pragma unroll
        for (int tm = 0; tm < 3; tm++) {
            bf16x8 af1 = ldfrag(wl1 + (tm*3+ks)*512);
            bf16x8 af2 = ldfrag(wl2 + (tm*3+ks)*512);
            acc1[tm][0] = __builtin_amdgcn_mfma_f32_16x16x32_bf16(af1, bfa0, acc1[tm][0], 0, 0, 0);
            acc1[tm][1] = __builtin_amdgcn_mfma_f32_16x16x32_bf16(af1, bfa1, acc1[tm][1], 0, 0, 0);
            acc2[tm][0] = __builtin_amdgcn_mfma_f32_16x16x32_bf16(af2, bfb0, acc2[tm][0], 0, 0, 0);
            acc2[tm][1] = __builtin_amdgcn_mfma_f32_16x16x32_bf16(af2, bfb1, acc2[tm][1], 0, 0, 0);
        }
    }
    __builtin_amdgcn_s_setprio(0);
    size_t ob = (size_t)b*CHW + hw0;
    float s = 0.f, q = 0.f;
    #pragma unroll
    for (int tm = 0; tm < 3; tm++) {
        #pragma unroll
        for (int xr = 0; xr < 2; xr++) {
            #pragma unroll
            for (int r = 0; r < 4; r++) {
                int o = mh*48 + tm*16 + r0i + r;
                float v = gelu_t(acc1[tm][xr][r] + b1[o]) + gelu_t(acc2[tm][xr][r] + b2[o]);
                out[ob + (size_t)o*HWSZ + cg*32 + xr*16 + ln] = f2bf(v);
                s += v; q += v*v;
            }
        }
    }
    #pragma unroll
    for (int off = 32; off > 0; off >>= 1) { s += __shfl_down(s, off); q += __shfl_down(q, off); }
    if (lane == 0) red[wv] = make_float2(s, q);
    __syncthreads();
    if (tid == 0) {
        for (int i = 1; i < 4; i++) { s += red[i].x; q += red[i].y; }
        part_out[b*49 + blockIdx.x] = make_float2(s, q);
    }
}

// ================= fused MLP: asm-pipelined weight loads (cannot be sunk) =================
// Per chunk: wait(w1) -> GEMM1 | bar | issue w2[ch] | mc-write (covers w2) | bar |
//            issue w1[ch+1] | wait vmcnt(9) (w2 done, w1next in flight) -> GEMM2.
__global__ __launch_bounds__(512, 4) void mlp_mfma(float* __restrict__ xio, const float2* __restrict__ part_in,
        const float* __restrict__ gam, const float* __restrict__ bet,
        const unsigned short* __restrict__ wbf, const float* __restrict__ b1, const float* __restrict__ b2) {
    __shared__ unsigned short xs[128][NP];   // 26624 B
    __shared__ unsigned short mc[128][NP];   // 26624 B
    __shared__ float gml[CC], btl[CC];
    int tid = threadIdx.x;
    int b0 = blockIdx.y, b1i = b0 + 32;
    int hw0 = blockIdx.x * 64;
    int lane = tid & 63, wv = tid >> 6;
    int mh = wv >> 2;                 // M-half: rows mh*48..mh*48+47
    int cg = wv & 3;                  // col-group: staged cols cg*32..cg*32+31
    const unsigned short* wbase = wbf + mh*4608 + lane*8;
    bf16x8 w1r[9], w2r[9];
    // issue w1[chunk 0] NOW — volatile asm, compiler cannot sink; covered by stats+staging
    #pragma unroll
    for (int i = 0; i < 9; i++) ldg_async(w1r[i], wbase + 4*9216 + i*512);
    float2 st0 = stats_from_parts<49>(part_in, b0);
    float2 st1 = stats_from_parts<49>(part_in, b1i);
    if (tid < CC) { gml[tid] = gam[tid]; btl[tid] = bet[tid]; }
    __syncthreads();
    {
        int col = tid & 63;
        int bsel0 = (tid >> 6) & 1;
        float2 st = bsel0 ? st1 : st0;
        size_t base = (size_t)(bsel0 ? b1i : b0)*CHW + hw0 + col;
        for (int c4 = (tid >> 7)*4; c4 < CC; c4 += 16) {
            unsigned int pk[2];
            #pragma unroll
            for (int j = 0; j < 4; j++) {
                int c = c4 + j;
                float rv = xio[base + (size_t)c*HWSZ];
                float a = st.y * gml[c];
                float bc = __builtin_fmaf(-st.x, a, btl[c]);
                unsigned short h = f2bf(__builtin_fmaf(rv, a, bc));
                if (j < 2) { if (j == 0) pk[0] = h; else pk[0] |= (unsigned int)h << 16; }
                else       { if (j == 2) pk[1] = h; else pk[1] |= (unsigned int)h << 16; }
            }
            *reinterpret_cast<uint2*>(&xs[bsel0*64 + col][c4]) = make_uint2(pk[0], pk[1]);
        }
    }
    __syncthreads();                   // xs fully staged
    int ln = lane & 15, k0 = (lane >> 4)*8;
    int r0i = (lane >> 4)*4;
    int xrow0 = cg*32 + ln;
    int xrow1 = xrow0 + 16;
    f32x4 ao[3][2];
    #pragma unroll
    for (int t = 0; t < 3; t++) { ao[t][0] = (f32x4){0,0,0,0}; ao[t][1] = (f32x4){0,0,0,0}; }
    #pragma unroll
    for (int ch = 0; ch < 4; ch++) {
        // ---- GEMM1: wait all outstanding (w1r for this chunk) ----
        wait_vm<0>();
        f32x4 c1[3][2];
        #pragma unroll
        for (int t = 0; t < 3; t++) { c1[t][0] = (f32x4){0,0,0,0}; c1[t][1] = (f32x4){0,0,0,0}; }
        __builtin_amdgcn_s_setprio(1);
        #pragma unroll
        for (int ks = 0; ks < 3; ks++) {
            bf16x8 bfa = ldfrag(&xs[xrow0][ks*32+k0]);
            bf16x8 bfb = ldfrag(&xs[xrow1][ks*32+k0]);
            #pragma unroll
            for (int tm = 0; tm < 3; tm++) {
                c1[tm][0] = __builtin_amdgcn_mfma_f32_16x16x32_bf16(w1r[tm*3+ks], bfa, c1[tm][0], 0, 0, 0);
                c1[tm][1] = __builtin_amdgcn_mfma_f32_16x16x32_bf16(w1r[tm*3+ks], bfb, c1[tm][1], 0, 0, 0);
            }
        }
        __builtin_amdgcn_s_setprio(0);
        __syncthreads();               // prev chunk's GEMM2 done reading mc
        // ---- issue w2[ch]: latency covered by the gelu/mc-write VALU below ----
        #pragma unroll
        for (int i = 0; i < 9; i++) ldg_async(w2r[i], wbase + (8+ch)*9216 + i*512);
        #pragma unroll
        for (int tm = 0; tm < 3; tm++) {
            int d0 = mh*48 + tm*16 + r0i;
            int dch = ch*CC + d0;
            unsigned short m0 = f2bf(gelu_t(c1[tm][0][0] + b1[dch+0]));
            unsigned short m1 = f2bf(gelu_t(c1[tm][0][1] + b1[dch+1]));
            unsigned short m2 = f2bf(gelu_t(c1[tm][0][2] + b1[dch+2]));
            unsigned short m3 = f2bf(gelu_t(c1[tm][0][3] + b1[dch+3]));
            *reinterpret_cast<uint2*>(&mc[xrow0][d0]) =
                make_uint2((unsigned int)m0 | ((unsigned int)m1 << 16),
                           (unsigned int)m2 | ((unsigned int)m3 << 16));
            unsigned short n0v = f2bf(gelu_t(c1[tm][1][0] + b1[dch+0]));
            unsigned short n1v = f2bf(gelu_t(c1[tm][1][1] + b1[dch+1]));
            unsigned short n2v = f2bf(gelu_t(c1[tm][1][2] + b1[dch+2]));
            unsigned short n3v = f2bf(gelu_t(c1[tm][1][3] + b1[dch+3]));
            *reinterpret_cast<uint2*>(&mc[xrow1][d0]) =
                make_uint2((unsigned int)n0v | ((unsigned int)n1v << 16),
                           (unsigned int)n2v | ((unsigned int)n3v << 16));
        }
        __syncthreads();               // mc ready
        // ---- issue w1[ch+1], then wait only w2 (9 newest = w1next stay in flight) ----
        if (ch < 3) {
            #pragma unroll
            for (int i = 0; i < 9; i++) ldg_async(w1r[i], wbase + (5+ch)*9216 + i*512);
            wait_vm<9>();
        } else {
            wait_vm<0>();
        }
        // ---- GEMM2 with w2r; w1next latency hidden under these MFMAs ----
        __builtin_amdgcn_s_setprio(1);
        #pragma unroll
        for (int ks = 0; ks < 3; ks++) {
            bf16x8 bfa = ldfrag(&mc[xrow0][ks*32+k0]);
            bf16x8 bfb = ldfrag(&mc[xrow1][ks*32+k0]);
            #pragma unroll
            for (int tm = 0; tm < 3; tm++) {
                ao[tm][0] = __builtin_amdgcn_mfma_f32_16x16x32_bf16(w2r[tm*3+ks], bfa, ao[tm][0], 0, 0, 0);
                ao[tm][1] = __builtin_amdgcn_mfma_f32_16x16x32_bf16(w2r[tm*3+ks], bfb, ao[tm][1], 0, 0, 0);
            }
        }
        __builtin_amdgcn_s_setprio(0);
    }
    int bsel = cg >> 1;
    size_t ob = (size_t)(bsel ? b1i : b0)*CHW + hw0 + (cg & 1)*32 + ln;
    #pragma unroll
    for (int tm = 0; tm < 3; tm++) {
        #pragma unroll
        for (int r = 0; r < 4; r++) {
            int o = mh*48 + tm*16 + r0i + r;
            size_t i0 = ob + (size_t)o*HWSZ;
            float bo = b2[o];
            xio[i0]      = xio[i0]      + bo + ao[tm][0][r];
            xio[i0 + 16] = xio[i0 + 16] + bo + ao[tm][1][r];
        }
    }
}

extern "C" void kernel_launch(void* const* d_in, const int* in_sizes, int n_in,
                              void* d_out, int out_size, void* d_ws, size_t ws_size,
                              hipStream_t stream) {
    (void)in_sizes; (void)n_in; (void)out_size; (void)ws_size;
    const float* x    = (const float*)d_in[0];
    const float* n1g  = (const float*)d_in[1];
    const float* n1b  = (const float*)d_in[2];
    const float* c1w  = (const float*)d_in[3];
    const float* c1b  = (const float*)d_in[4];
    const float* g1g  = (const float*)d_in[5];
    const float* g1b  = (const float*)d_in[6];
    const float* dww  = (const float*)d_in[7];
    const float* dwb  = (const float*)d_in[8];
    const float* g2g  = (const float*)d_in[9];
    const float* g2b  = (const float*)d_in[10];
    const float* tau1 = (const float*)d_in[11];
    const float* vth1 = (const float*)d_in[12];
    const float* tau2 = (const float*)d_in[13];
    const float* vth2 = (const float*)d_in[14];
    const float* c21w = (const float*)d_in[15];
    const float* c21b = (const float*)d_in[16];
    const float* c22w = (const float*)d_in[17];
    const float* c22b = (const float*)d_in[18];
    const float* g3g  = (const float*)d_in[19];
    const float* g3b  = (const float*)d_in[20];
    const float* c3w  = (const float*)d_in[21];
    const float* c3b  = (const float*)d_in[22];
    const float* n2g  = (const float*)d_in[23];
    const float* n2b  = (const float*)d_in[24];
    const float* f1w  = (const float*)d_in[25];
    const float* f1b  = (const float*)d_in[26];
    const float* f2w  = (const float*)d_in[27];
    const float* f2b  = (const float*)d_in[28];
    float* out = (float*)d_out;

    unsigned short* A   = (unsigned short*)d_ws;     // 3 bf16 NTOT buffers
    unsigned short* Bb  = A  + NTOT;
    unsigned short* Cc  = Bb + NTOT;
    unsigned short* WBF = Cc + NTOT;                 // 110592 bf16 weights (fragment-repacked)
    float2* part0 = (float2*)(WBF + 110592);         // x stats partials      (64*32)
    float2* part1 = part0 + 64*32;                   // conv1 out partials    (64*49)
    float2* part2 = part1 + 64*49;                   // dw out partials       (64*96)
    float2* part3 = part2 + 64*96;                   // dual out partials     (64*49)
    float2* part4 = part3 + 64*49;                   // x2 partials           (64*49)

    const unsigned short* Wc1  = WBF;
    const unsigned short* Wc21 = WBF + 9216;
    const unsigned short* Wc22 = WBF + 18432;
    const unsigned short* Wc3  = WBF + 27648;

    dim3 gStat(S_SPLIT, BB);
    dim3 gPair(HWSZ/64, BB/2);      // (49, 32)
    dim3 gSing(HWSZ/64, BB);        // (49, 64)

    wconv<<<432,256,0,stream>>>(c1w, c21w, c22w, c3w, f1w, f2w, WBF);
    gn_partial<<<gStat,256,0,stream>>>(x, part0);
    convk<false,false,S_SPLIT><<<gPair,256,0,stream>>>(x, Wc1, c1b, part0, n1g, n1b, nullptr, A, part1);  // t1 -> A
    dw_fused<<<BB*CC,256,0,stream>>>(A, dww, dwb, part1, g1g, g1b, Bb, part2);                            // t2 -> B
    lif_hw<<<BB*CC,64,0,stream>>>(Bb, A, Cc, part2, g2g, g2b, tau1, vth1, tau2, vth2);                    // x_lr->A, x_td->C
    dual_mfma<<<gSing,256,0,stream>>>(A, Cc, Wc21, c21b, Wc22, c22b, Bb, part3);                          // h3 -> B
    convk<true,true,49><<<gPair,256,0,stream>>>(Bb, Wc3, c3b, part3, g3g, g3b, x, out, part4);            // x2 -> d_out
    mlp_mfma<<<gPair,512,0,stream>>>(out, part4, n2g, n2b, WBF, f1b, f2b);                                // out = x2 + mlp
}

// Round 11
// 299.363 us; speedup vs baseline: 1.0373x; 1.0373x over previous
//
#include <hip/hip_runtime.h>

#define BB 64
#define CC 96
#define HH 56
#define WW 56
#define HWSZ (HH*WW)          // 3136
#define CHW (CC*HWSZ)         // 301056
#define NTOT ((size_t)BB*CHW) // 19267584
#define S_SPLIT 32
#define CHUNK (CHW/S_SPLIT)   // 9408
#define HD 384
#define NP 104                // LDS row pitch (ushorts): 208B rows, 16B-aligned

typedef float f32x4  __attribute__((ext_vector_type(4)));
typedef short bf16x8 __attribute__((ext_vector_type(8)));
typedef unsigned short u16x4 __attribute__((ext_vector_type(4)));

__device__ __forceinline__ unsigned short f2bf(float f) {
    unsigned int u = __float_as_uint(f);
    u = (u + 0x7FFFu + ((u >> 16) & 1u)) >> 16;   // RNE
    return (unsigned short)u;
}
// HW packed convert: 2 f32 -> packed 2x bf16 (RNE), ONE VALU op (vs ~10 for f2bf pair)
__device__ __forceinline__ unsigned int cvtpk(float lo, float hi) {
    unsigned int r;
    asm("v_cvt_pk_bf16_f32 %0, %1, %2" : "=v"(r) : "v"(lo), "v"(hi));
    return r;
}
__device__ __forceinline__ unsigned short cvt1(float x) {
    return (unsigned short)cvtpk(x, x);
}
__device__ __forceinline__ float bf2f(unsigned short u) {
    return __uint_as_float(((unsigned int)u) << 16);
}
// tanh-approx GELU: |err| vs exact erf-gelu ~1e-3.
__device__ __forceinline__ float gelu_t(float x) {
    float s = x*x;
    float q = __builtin_fmaf(s, 0.102943f, 2.3021953f) * x;   // 2y*log2e
    float t = exp2f(q);
    float r = __builtin_amdgcn_rcpf(1.0f + t);
    return __builtin_fmaf(-x, r, x);                          // x - x/(1+e^{2y})
}
__device__ __forceinline__ bf16x8 ldfrag(const unsigned short* p) {
    return *reinterpret_cast<const bf16x8*>(p);
}
// inline GN-stats finalize: every wave reduces the producer's partial sums itself
template<int NPART>
__device__ __forceinline__ float2 stats_from_parts(const float2* __restrict__ part, int b) {
    int lane = threadIdx.x & 63;
    float s = 0.f, q = 0.f;
    for (int i = lane; i < NPART; i += 64) {
        float2 v = part[b*NPART + i];
        s += v.x; q += v.y;
    }
    #pragma unroll
    for (int off = 32; off > 0; off >>= 1) {
        s += __shfl_down(s, off);
        q += __shfl_down(q, off);
    }
    s = __shfl(s, 0); q = __shfl(q, 0);
    float mean = s / (float)CHW;
    float var  = q / (float)CHW - mean*mean;
    return make_float2(mean, rsqrtf(var + 1e-5f));
}

// ================= weight pre-convert + MFMA-fragment repack (once) =================
__global__ __launch_bounds__(256) void wconv(const float* __restrict__ c1w, const float* __restrict__ c21w,
        const float* __restrict__ c22w, const float* __restrict__ c3w,
        const float* __restrict__ f1w, const float* __restrict__ f2w,
        unsigned short* __restrict__ wbf) {
    int i = blockIdx.x*256 + threadIdx.x;           // 110592 total
    int blk = i / 9216;
    int idx = i - blk*9216;
    int tm   = idx / 1536;
    int rem  = idx - tm*1536;
    int ks   = rem / 512;
    int rem2 = rem - ks*512;
    int lane = rem2 >> 3;
    int j    = rem2 & 7;
    int row = tm*16 + (lane & 15);
    int col = ks*32 + (lane >> 4)*8 + j;
    float v;
    if      (blk == 0) v = c1w [row*CC + col];
    else if (blk == 1) v = c21w[row*CC + col];
    else if (blk == 2) v = c22w[row*CC + col];
    else if (blk == 3) v = c3w [row*CC + col];
    else if (blk <  8) v = f1w[((blk-4)*CC + row)*CC + col];
    else               v = f2w[row*HD + (blk-8)*CC + col];
    wbf[i] = f2bf(v);
}

// ================= GN stats on x, float4 =================
__global__ __launch_bounds__(256) void gn_partial(const float* __restrict__ in, float2* __restrict__ part) {
    int b = blockIdx.y, s = blockIdx.x;
    const float4* p = (const float4*)(in + (size_t)b*CHW + (size_t)s*CHUNK);
    float sum = 0.f, sq = 0.f;
    for (int i = threadIdx.x; i < CHUNK/4; i += 256) {
        float4 v = p[i];
        sum += v.x+v.y+v.z+v.w;
        sq  += v.x*v.x+v.y*v.y+v.z*v.z+v.w*v.w;
    }
    #pragma unroll
    for (int off = 32; off > 0; off >>= 1) {
        sum += __shfl_down(sum, off);
        sq  += __shfl_down(sq,  off);
    }
    __shared__ float2 red[4];
    int wid = threadIdx.x >> 6, lane = threadIdx.x & 63;
    if (lane == 0) red[wid] = make_float2(sum, sq);
    __syncthreads();
    if (threadIdx.x == 0) {
        for (int i = 1; i < 4; i++) { sum += red[i].x; sq += red[i].y; }
        part[b*S_SPLIT + s] = make_float2(sum, sq);
    }
}

// ================= batch-paired 1x1 conv, M-split waves, pre-scaled affine, cvt_pk =================
template<bool IN_BF, bool OUT_RES, int NPART>
__global__ __launch_bounds__(256) void convk(const void* __restrict__ in_,
        const unsigned short* __restrict__ wbf, const float* __restrict__ bias,
        const float2* __restrict__ part_in, const float* __restrict__ gam, const float* __restrict__ bet,
        const float* __restrict__ res, void* __restrict__ out_, float2* __restrict__ part_out) {
    __shared__ unsigned short xs[128][NP];
    __shared__ float af0[CC], bf0[CC], af1[CC], bf1[CC];
    __shared__ float2 red[4];
    int tid = threadIdx.x;
    int b0 = blockIdx.y, b1 = b0 + 32;
    int hw0 = blockIdx.x * 64;
    int lane = tid & 63, wv = tid >> 6;
    int mh = wv >> 1, cg = wv & 1;
    // hoist weight frags: latency covered by stats reduce + staging + barrier
    bf16x8 wfr[9];
    {
        const unsigned short* wl = wbf + mh*4608 + lane*8;
        #pragma unroll
        for (int i = 0; i < 9; i++) wfr[i] = ldfrag(wl + i*512);
    }
    float2 st0 = stats_from_parts<NPART>(part_in, b0);
    float2 st1 = stats_from_parts<NPART>(part_in, b1);
    if (tid < CC) {
        float a0 = st0.y * gam[tid];
        af0[tid] = a0; bf0[tid] = __builtin_fmaf(-st0.x, a0, bet[tid]);
        float a1 = st1.y * gam[tid];
        af1[tid] = a1; bf1[tid] = __builtin_fmaf(-st1.x, a1, bet[tid]);
    }
    __syncthreads();
    int col = tid & 63;
    for (int c4 = (tid >> 6)*4; c4 < CC; c4 += 16) {
        float v0[4], v1[4];
        #pragma unroll
        for (int j = 0; j < 4; j++) {
            int c = c4 + j;
            size_t off0 = (size_t)b0*CHW + (size_t)c*HWSZ + hw0 + col;
            size_t off1 = (size_t)b1*CHW + (size_t)c*HWSZ + hw0 + col;
            float r0 = IN_BF ? bf2f(((const unsigned short*)in_)[off0]) : ((const float*)in_)[off0];
            float r1 = IN_BF ? bf2f(((const unsigned short*)in_)[off1]) : ((const float*)in_)[off1];
            v0[j] = __builtin_fmaf(r0, af0[c], bf0[c]);
            v1[j] = __builtin_fmaf(r1, af1[c], bf1[c]);
        }
        *reinterpret_cast<uint2*>(&xs[col][c4])    = make_uint2(cvtpk(v0[0],v0[1]), cvtpk(v0[2],v0[3]));
        *reinterpret_cast<uint2*>(&xs[64+col][c4]) = make_uint2(cvtpk(v1[0],v1[1]), cvtpk(v1[2],v1[3]));
    }
    __syncthreads();
    int ln = lane & 15, k0 = (lane >> 4)*8, r0i = (lane >> 4)*4;
    f32x4 acc[3][4];
    #pragma unroll
    for (int t = 0; t < 3; t++)
        #pragma unroll
        for (int x = 0; x < 4; x++) acc[t][x] = (f32x4){0,0,0,0};
    __builtin_amdgcn_s_setprio(1);
    #pragma unroll
    for (int ks = 0; ks < 3; ks++) {
        bf16x8 bfr[4];
        #pragma unroll
        for (int xr = 0; xr < 4; xr++) bfr[xr] = ldfrag(&xs[cg*64 + xr*16 + ln][ks*32+k0]);
        #pragma unroll
        for (int tm = 0; tm < 3; tm++) {
            #pragma unroll
            for (int xr = 0; xr < 4; xr++)
                acc[tm][xr] = __builtin_amdgcn_mfma_f32_16x16x32_bf16(wfr[tm*3+ks], bfr[xr], acc[tm][xr], 0, 0, 0);
        }
    }
    __builtin_amdgcn_s_setprio(0);
    size_t obase = (size_t)(cg ? b1 : b0)*CHW + hw0;
    float s = 0.f, q = 0.f;
    #pragma unroll
    for (int tm = 0; tm < 3; tm++) {
        #pragma unroll
        for (int xr = 0; xr < 4; xr++) {
            #pragma unroll
            for (int r = 0; r < 4; r++) {
                int o = mh*48 + tm*16 + r0i + r;
                size_t idx = obase + (size_t)o*HWSZ + xr*16 + ln;
                float v = acc[tm][xr][r] + bias[o];
                if (OUT_RES) { v += res[idx]; ((float*)out_)[idx] = v; }
                else         { ((unsigned short*)out_)[idx] = cvt1(v); }
                s += v; q += v*v;
            }
        }
    }
    #pragma unroll
    for (int off = 32; off > 0; off >>= 1) { s += __shfl_down(s, off); q += __shfl_down(q, off); }
    if (lane == 0) red[wv] = make_float2(s, q);
    __syncthreads();
    if (tid == 0) {
        part_out[b0*49 + blockIdx.x] = make_float2(red[0].x + red[2].x, red[0].y + red[2].y);
        part_out[b1*49 + blockIdx.x] = make_float2(red[1].x + red[3].x, red[1].y + red[3].y);
    }
}

// ================= depthwise 3x3: fused gelu(gn(t1)), inline stats, stats epilogue =================
__global__ __launch_bounds__(256) void dw_fused(const unsigned short* __restrict__ t1,
        const float* __restrict__ dww, const float* __restrict__ dwb,
        const float2* __restrict__ part_in, const float* __restrict__ gam, const float* __restrict__ bet,
        unsigned short* __restrict__ t2, float2* __restrict__ part_out) {
    __shared__ float tile[HH*57];
    __shared__ float2 red[4];
    int bc = blockIdx.x;
    int b = bc / CC, c = bc - b*CC;
    int tid = threadIdx.x;
    float2 st = stats_from_parts<49>(part_in, b);
    float ga = gam[c]*st.y;
    float bb = __builtin_fmaf(-st.x, ga, bet[c]);
    const unsigned short* ip = t1 + (size_t)bc*HWSZ;
    for (int i = tid; i < HWSZ; i += 256) {
        float v = __builtin_fmaf(bf2f(ip[i]), ga, bb);
        tile[(i/WW)*57 + (i%WW)] = gelu_t(v);
    }
    __syncthreads();
    float w00=dww[c*9+0],w01=dww[c*9+1],w02=dww[c*9+2],
          w10=dww[c*9+3],w11=dww[c*9+4],w12=dww[c*9+5],
          w20=dww[c*9+6],w21=dww[c*9+7],w22=dww[c*9+8];
    float bs = dwb[c];
    unsigned short* op = t2 + (size_t)bc*HWSZ;
    float s = 0.f, q = 0.f;
    for (int i = tid; i < HWSZ; i += 256) {
        int h = i/WW, w_ = i - h*WW;
        float acc = bs;
        int up = h > 0, dn = h < HH-1, lf = w_ > 0, rt = w_ < WW-1;
        const float* rm = &tile[(h-1)*57 + w_];
        const float* r0p = &tile[h*57 + w_];
        const float* rp = &tile[(h+1)*57 + w_];
        if (up) { if (lf) acc += rm[-1]*w00; acc += rm[0]*w01; if (rt) acc += rm[1]*w02; }
        if (lf) acc += r0p[-1]*w10;
        acc += r0p[0]*w11;
        if (rt) acc += r0p[1]*w12;
        if (dn) { if (lf) acc += rp[-1]*w20; acc += rp[0]*w21; if (rt) acc += rp[1]*w22; }
        op[i] = cvt1(acc);
        s += acc; q += acc*acc;
    }
    #pragma unroll
    for (int off = 32; off > 0; off >>= 1) { s += __shfl_down(s, off); q += __shfl_down(q, off); }
    int wid = tid >> 6, lane = tid & 63;
    if (lane == 0) red[wid] = make_float2(s, q);
    __syncthreads();
    if (tid == 0) {
        for (int i = 1; i < 4; i++) { s += red[i].x; q += red[i].y; }
        part_out[bc] = make_float2(s, q);   // indexed [b*96+c]
    }
}

// ================= merged LIF: one gelu(gn) pass, bf16 LDS plane =================
__global__ __launch_bounds__(64) void lif_hw(const unsigned short* __restrict__ t2,
        unsigned short* __restrict__ xlr, unsigned short* __restrict__ xtd,
        const float2* __restrict__ part_in, const float* __restrict__ gam, const float* __restrict__ bet,
        const float* __restrict__ tau1p, const float* __restrict__ vth1p,
        const float* __restrict__ tau2p, const float* __restrict__ vth2p) {
    __shared__ unsigned short tile[HH*58];
    int bc = blockIdx.x;
    int b = bc / CC, c = bc - b*CC;
    int tid = threadIdx.x;
    float2 st = stats_from_parts<96>(part_in, b);
    float ga = gam[c]*st.y;
    float bb = __builtin_fmaf(-st.x, ga, bet[c]);
    const unsigned short* ip = t2 + (size_t)bc*HWSZ;
    for (int i = tid; i < HWSZ/4; i += 64) {
        u16x4 v = *reinterpret_cast<const u16x4*>(ip + i*4);
        int h = i / 14;
        int w0 = (i - h*14)*4;
        unsigned short* tp = &tile[h*58 + w0];
        #pragma unroll
        for (int j = 0; j < 4; j++)
            tp[j] = cvt1(gelu_t(__builtin_fmaf(bf2f((unsigned short)v[j]), ga, bb)));
    }
    __syncthreads();
    const float tau1 = *tau1p, vth1 = *vth1p;
    if (tid < WW) {
        float u = 0.f, o = 0.f;
        unsigned short* op = xlr + (size_t)bc*HWSZ + tid;
        for (int h = 0; h < HH; h++) {
            float xv = bf2f(tile[h*58 + tid]);
            u = xv + tau1*u*(1.f - o);
            o = (u - vth1 > 0.f) ? 1.f : 0.f;
            op[h*WW] = (o != 0.f) ? (unsigned short)0x3F80 : (unsigned short)0;
        }
    }
    __syncthreads();
    const float tau2 = *tau2p, vth2 = *vth2p;
    if (tid < HH) {
        float u = 0.f, o = 0.f;
        int off = tid*58;
        for (int w_ = 0; w_ < WW; w_++) {
            float xv = bf2f(tile[off + w_]);
            u = xv + tau2*u*(1.f - o);
            o = (u - vth2 > 0.f) ? 1.f : 0.f;
            tile[off + w_] = (o != 0.f) ? (unsigned short)0x3F80 : (unsigned short)0;
        }
    }
    __syncthreads();
    unsigned int* op32 = (unsigned int*)(xtd + (size_t)bc*HWSZ);
    for (int i = tid; i < HWSZ/2; i += 64) {
        int h = i / 28;
        int w0 = (i - h*28)*2;
        op32[i] = (unsigned int)tile[h*58 + w0] | ((unsigned int)tile[h*58 + w0 + 1] << 16);
    }
}

// ================= dual conv, M-split waves, stats epilogue =================
__global__ __launch_bounds__(256) void dual_mfma(const unsigned short* __restrict__ xa_g, const unsigned short* __restrict__ xb_g,
        const unsigned short* __restrict__ w1bf, const float* __restrict__ b1,
        const unsigned short* __restrict__ w2bf, const float* __restrict__ b2,
        unsigned short* __restrict__ out, float2* __restrict__ part_out) {
    __shared__ unsigned short xa[64][NP];
    __shared__ unsigned short xb[64][NP];
    __shared__ float2 red[4];
    int tid = threadIdx.x;
    int b = blockIdx.y;
    int hw0 = blockIdx.x * 64;
    int col = tid & 63;
    const unsigned short* ap = xa_g + (size_t)b*CHW + hw0 + col;
    const unsigned short* bp = xb_g + (size_t)b*CHW + hw0 + col;
    for (int c4 = (tid >> 6)*4; c4 < CC; c4 += 16) {
        unsigned short a0 = ap[(size_t)(c4+0)*HWSZ], a1v = ap[(size_t)(c4+1)*HWSZ];
        unsigned short a2 = ap[(size_t)(c4+2)*HWSZ], a3 = ap[(size_t)(c4+3)*HWSZ];
        unsigned short b0v = bp[(size_t)(c4+0)*HWSZ], b1v = bp[(size_t)(c4+1)*HWSZ];
        unsigned short b2v = bp[(size_t)(c4+2)*HWSZ], b3v = bp[(size_t)(c4+3)*HWSZ];
        *reinterpret_cast<uint2*>(&xa[col][c4]) =
            make_uint2((unsigned int)a0 | ((unsigned int)a1v << 16), (unsigned int)a2 | ((unsigned int)a3 << 16));
        *reinterpret_cast<uint2*>(&xb[col][c4]) =
            make_uint2((unsigned int)b0v | ((unsigned int)b1v << 16), (unsigned int)b2v | ((unsigned int)b3v << 16));
    }
    __syncthreads();
    int lane = tid & 63, wv = tid >> 6;
    int mh = wv >> 1, cg = wv & 1;
    int ln = lane & 15, k0 = (lane >> 4)*8, r0i = (lane >> 4)*4;
    const unsigned short* wl1 = w1bf + mh*4608 + lane*8;
    const unsigned short* wl2 = w2bf + mh*4608 + lane*8;
    f32x4 acc1[3][2], acc2[3][2];
    #pragma unroll
    for (int t = 0; t < 3; t++) {
        acc1[t][0] = (f32x4){0,0,0,0}; acc1[t][1] = (f32x4){0,0,0,0};
        acc2[t][0] = (f32x4){0,0,0,0}; acc2[t][1] = (f32x4){0,0,0,0};
    }
    __builtin_amdgcn_s_setprio(1);
    #pragma unroll
    for (int ks = 0; ks < 3; ks++) {
        bf16x8 bfa0 = ldfrag(&xa[cg*32 + ln][ks*32+k0]);
        bf16x8 bfa1 = ldfrag(&xa[cg*32 + 16 + ln][ks*32+k0]);
        bf16x8 bfb0 = ldfrag(&xb[cg*32 + ln][ks*32+k0]);
        bf16x8 bfb1 = ldfrag(&xb[cg*32 + 16 + ln][ks*32+k0]);
        #pragma unroll
        for (int tm = 0; tm < 3; tm++) {
            bf16x8 af1 = ldfrag(wl1 + (tm*3+ks)*512);
            bf16x8 af2 = ldfrag(wl2 + (tm*3+ks)*512);
            acc1[tm][0] = __builtin_amdgcn_mfma_f32_16x16x32_bf16(af1, bfa0, acc1[tm][0], 0, 0, 0);
            acc1[tm][1] = __builtin_amdgcn_mfma_f32_16x16x32_bf16(af1, bfa1, acc1[tm][1], 0, 0, 0);
            acc2[tm][0] = __builtin_amdgcn_mfma_f32_16x16x32_bf16(af2, bfb0, acc2[tm][0], 0, 0, 0);
            acc2[tm][1] = __builtin_amdgcn_mfma_f32_16x16x32_bf16(af2, bfb1, acc2[tm][1], 0, 0, 0);
        }
    }
    __builtin_amdgcn_s_setprio(0);
    size_t ob = (size_t)b*CHW + hw0;
    float s = 0.f, q = 0.f;
    #pragma unroll
    for (int tm = 0; tm < 3; tm++) {
        #pragma unroll
        for (int xr = 0; xr < 2; xr++) {
            #pragma unroll
            for (int r = 0; r < 4; r++) {
                int o = mh*48 + tm*16 + r0i + r;
                float v = gelu_t(acc1[tm][xr][r] + b1[o]) + gelu_t(acc2[tm][xr][r] + b2[o]);
                out[ob + (size_t)o*HWSZ + cg*32 + xr*16 + ln] = cvt1(v);
                s += v; q += v*v;
            }
        }
    }
    #pragma unroll
    for (int off = 32; off > 0; off >>= 1) { s += __shfl_down(s, off); q += __shfl_down(q, off); }
    if (lane == 0) red[wv] = make_float2(s, q);
    __syncthreads();
    if (tid == 0) {
        for (int i = 1; i < 4; i++) { s += red[i].x; q += red[i].y; }
        part_out[b*49 + blockIdx.x] = make_float2(s, q);
    }
}

// ================= fused MLP, 512 threads, M-split, pre-scaled affine + cvt_pk =================
__global__ __launch_bounds__(512, 4) void mlp_mfma(float* __restrict__ xio, const float2* __restrict__ part_in,
        const float* __restrict__ gam, const float* __restrict__ bet,
        const unsigned short* __restrict__ wbf, const float* __restrict__ b1, const float* __restrict__ b2) {
    __shared__ unsigned short xs[128][NP];   // 26624 B
    __shared__ unsigned short mc[128][NP];   // 26624 B
    __shared__ float afc[2][CC], bfc[2][CC];
    int tid = threadIdx.x;
    int b0 = blockIdx.y, b1i = b0 + 32;
    int hw0 = blockIdx.x * 64;
    int lane = tid & 63, wv = tid >> 6;
    int mh = wv >> 2;                 // M-half: rows mh*48..mh*48+47
    int cg = wv & 3;                  // col-group: staged cols cg*32..cg*32+31
    float2 st0 = stats_from_parts<49>(part_in, b0);
    float2 st1 = stats_from_parts<49>(part_in, b1i);
    if (tid < CC) {
        float a0 = st0.y * gam[tid];
        afc[0][tid] = a0; bfc[0][tid] = __builtin_fmaf(-st0.x, a0, bet[tid]);
        float a1 = st1.y * gam[tid];
        afc[1][tid] = a1; bfc[1][tid] = __builtin_fmaf(-st1.x, a1, bet[tid]);
    }
    __syncthreads();
    {
        int col = tid & 63;
        int bsel0 = (tid >> 6) & 1;
        size_t base = (size_t)(bsel0 ? b1i : b0)*CHW + hw0 + col;
        for (int c4 = (tid >> 7)*4; c4 < CC; c4 += 16) {
            float v[4];
            #pragma unroll
            for (int j = 0; j < 4; j++) {
                int c = c4 + j;
                float rv = xio[base + (size_t)c*HWSZ];
                v[j] = __builtin_fmaf(rv, afc[bsel0][c], bfc[bsel0][c]);
            }
            *reinterpret_cast<uint2*>(&xs[bsel0*64 + col][c4]) =
                make_uint2(cvtpk(v[0],v[1]), cvtpk(v[2],v[3]));
        }
    }
    __syncthreads();                   // xs fully staged
    int ln = lane & 15, k0 = (lane >> 4)*8;
    int r0i = (lane >> 4)*4;
    int xrow0 = cg*32 + ln;
    int xrow1 = xrow0 + 16;
    f32x4 ao[3][2];
    #pragma unroll
    for (int t = 0; t < 3; t++) { ao[t][0] = (f32x4){0,0,0,0}; ao[t][1] = (f32x4){0,0,0,0}; }
    for (int ch = 0; ch < 4; ch++) {
        const unsigned short* w1l = wbf + (4+ch)*9216 + mh*4608 + lane*8;
        const unsigned short* w2l = wbf + (8+ch)*9216 + mh*4608 + lane*8;
        f32x4 c1[3][2];
        #pragma unroll
        for (int t = 0; t < 3; t++) { c1[t][0] = (f32x4){0,0,0,0}; c1[t][1] = (f32x4){0,0,0,0}; }
        __builtin_amdgcn_s_setprio(1);
        #pragma unroll
        for (int ks = 0; ks < 3; ks++) {
            bf16x8 bfa = ldfrag(&xs[xrow0][ks*32+k0]);
            bf16x8 bfb = ldfrag(&xs[xrow1][ks*32+k0]);
            #pragma unroll
            for (int tm = 0; tm < 3; tm++) {
                bf16x8 af = ldfrag(w1l + (tm*3+ks)*512);
                c1[tm][0] = __builtin_amdgcn_mfma_f32_16x16x32_bf16(af, bfa, c1[tm][0], 0, 0, 0);
                c1[tm][1] = __builtin_amdgcn_mfma_f32_16x16x32_bf16(af, bfb, c1[tm][1], 0, 0, 0);
            }
        }
        __builtin_amdgcn_s_setprio(0);
        #pragma unroll
        for (int tm = 0; tm < 3; tm++) {
            int d0 = mh*48 + tm*16 + r0i;
            int dch = ch*CC + d0;
            float g0 = gelu_t(c1[tm][0][0] + b1[dch+0]);
            float g1 = gelu_t(c1[tm][0][1] + b1[dch+1]);
            float g2 = gelu_t(c1[tm][0][2] + b1[dch+2]);
            float g3 = gelu_t(c1[tm][0][3] + b1[dch+3]);
            *reinterpret_cast<uint2*>(&mc[xrow0][d0]) = make_uint2(cvtpk(g0,g1), cvtpk(g2,g3));
            float h0 = gelu_t(c1[tm][1][0] + b1[dch+0]);
            float h1 = gelu_t(c1[tm][1][1] + b1[dch+1]);
            float h2 = gelu_t(c1[tm][1][2] + b1[dch+2]);
            float h3 = gelu_t(c1[tm][1][3] + b1[dch+3]);
            *reinterpret_cast<uint2*>(&mc[xrow1][d0]) = make_uint2(cvtpk(h0,h1), cvtpk(h2,h3));
        }
        __syncthreads();               // mc complete (both M-halves)
        __builtin_amdgcn_s_setprio(1);
        #pragma unroll
        for (int ks = 0; ks < 3; ks++) {
            bf16x8 bfa = ldfrag(&mc[xrow0][ks*32+k0]);
            bf16x8 bfb = ldfrag(&mc[xrow1][ks*32+k0]);
            #pragma unroll
            for (int tm = 0; tm < 3; tm++) {
                bf16x8 af = ldfrag(w2l + (tm*3+ks)*512);
                ao[tm][0] = __builtin_amdgcn_mfma_f32_16x16x32_bf16(af, bfa, ao[tm][0], 0, 0, 0);
                ao[tm][1] = __builtin_amdgcn_mfma_f32_16x16x32_bf16(af, bfb, ao[tm][1], 0, 0, 0);
            }
        }
        __builtin_amdgcn_s_setprio(0);
        __syncthreads();               // GEMM2 reads done before next chunk overwrites mc
    }
    int bsel = cg >> 1;
    size_t ob = (size_t)(bsel ? b1i : b0)*CHW + hw0 + (cg & 1)*32 + ln;
    #pragma unroll
    for (int tm = 0; tm < 3; tm++) {
        #pragma unroll
        for (int r = 0; r < 4; r++) {
            int o = mh*48 + tm*16 + r0i + r;
            size_t i0 = ob + (size_t)o*HWSZ;
            float bo = b2[o];
            xio[i0]      = xio[i0]      + bo + ao[tm][0][r];
            xio[i0 + 16] = xio[i0 + 16] + bo + ao[tm][1][r];
        }
    }
}

extern "C" void kernel_launch(void* const* d_in, const int* in_sizes, int n_in,
                              void* d_out, int out_size, void* d_ws, size_t ws_size,
                              hipStream_t stream) {
    (void)in_sizes; (void)n_in; (void)out_size; (void)ws_size;
    const float* x    = (const float*)d_in[0];
    const float* n1g  = (const float*)d_in[1];
    const float* n1b  = (const float*)d_in[2];
    const float* c1w  = (const float*)d_in[3];
    const float* c1b  = (const float*)d_in[4];
    const float* g1g  = (const float*)d_in[5];
    const float* g1b  = (const float*)d_in[6];
    const float* dww  = (const float*)d_in[7];
    const float* dwb  = (const float*)d_in[8];
    const float* g2g  = (const float*)d_in[9];
    const float* g2b  = (const float*)d_in[10];
    const float* tau1 = (const float*)d_in[11];
    const float* vth1 = (const float*)d_in[12];
    const float* tau2 = (const float*)d_in[13];
    const float* vth2 = (const float*)d_in[14];
    const float* c21w = (const float*)d_in[15];
    const float* c21b = (const float*)d_in[16];
    const float* c22w = (const float*)d_in[17];
    const float* c22b = (const float*)d_in[18];
    const float* g3g  = (const float*)d_in[19];
    const float* g3b  = (const float*)d_in[20];
    const float* c3w  = (const float*)d_in[21];
    const float* c3b  = (const float*)d_in[22];
    const float* n2g  = (const float*)d_in[23];
    const float* n2b  = (const float*)d_in[24];
    const float* f1w  = (const float*)d_in[25];
    const float* f1b  = (const float*)d_in[26];
    const float* f2w  = (const float*)d_in[27];
    const float* f2b  = (const float*)d_in[28];
    float* out = (float*)d_out;

    unsigned short* A   = (unsigned short*)d_ws;     // 3 bf16 NTOT buffers
    unsigned short* Bb  = A  + NTOT;
    unsigned short* Cc  = Bb + NTOT;
    unsigned short* WBF = Cc + NTOT;                 // 110592 bf16 weights (fragment-repacked)
    float2* part0 = (float2*)(WBF + 110592);         // x stats partials      (64*32)
    float2* part1 = part0 + 64*32;                   // conv1 out partials    (64*49)
    float2* part2 = part1 + 64*49;                   // dw out partials       (64*96)
    float2* part3 = part2 + 64*96;                   // dual out partials     (64*49)
    float2* part4 = part3 + 64*49;                   // x2 partials           (64*49)

    const unsigned short* Wc1  = WBF;
    const unsigned short* Wc21 = WBF + 9216;
    const unsigned short* Wc22 = WBF + 18432;
    const unsigned short* Wc3  = WBF + 27648;

    dim3 gStat(S_SPLIT, BB);
    dim3 gPair(HWSZ/64, BB/2);      // (49, 32)
    dim3 gSing(HWSZ/64, BB);        // (49, 64)

    wconv<<<432,256,0,stream>>>(c1w, c21w, c22w, c3w, f1w, f2w, WBF);
    gn_partial<<<gStat,256,0,stream>>>(x, part0);
    convk<false,false,S_SPLIT><<<gPair,256,0,stream>>>(x, Wc1, c1b, part0, n1g, n1b, nullptr, A, part1);  // t1 -> A
    dw_fused<<<BB*CC,256,0,stream>>>(A, dww, dwb, part1, g1g, g1b, Bb, part2);                            // t2 -> B
    lif_hw<<<BB*CC,64,0,stream>>>(Bb, A, Cc, part2, g2g, g2b, tau1, vth1, tau2, vth2);                    // x_lr->A, x_td->C
    dual_mfma<<<gSing,256,0,stream>>>(A, Cc, Wc21, c21b, Wc22, c22b, Bb, part3);                          // h3 -> B
    convk<true,true,49><<<gPair,256,0,stream>>>(Bb, Wc3, c3b, part3, g3g, g3b, x, out, part4);            // x2 -> d_out
    mlp_mfma<<<gPair,512,0,stream>>>(out, part4, n2g, n2b, WBF, f1b, f2b);                                // out = x2 + mlp
}